// Round 7
// baseline (544.052 us; speedup 1.0000x reference)
//
#include <hip/hip_runtime.h>
#include <hip/hip_cooperative_groups.h>
#include <stdint.h>

#pragma clang fp contract(off)

namespace cg = cooperative_groups;

#define BS 32
#define NB 64
#define NA 8400
#define NAP 8448          // NA padded to multiple of 64 (132 waves)
#define NC 80
#define TK 13
#define QCAP 640          // max in-box anchors per gt row (expected <=~400)
#define CMAX (QCAP + 32)  // + forced anchors
#define FORCED 32
#define NBLK 512
#define NTHR 256
#define TTOT (NBLK * NTHR)                    // 131072 threads, 2048 waves
#define NCAND (BS * NB * TK)                  // 26624
#define ZWORDS (2 * BS * NA + 3 * BS * NB + 16)

typedef float floatx4 __attribute__((ext_vector_type(4)));

// ---------- CIoU, numpy op order, no FMA contraction ----------
__device__ __forceinline__ float ciou_f(float g0, float g1, float g2, float g3,
                                        float p0, float p1, float p2, float p3) {
    const float E = 1e-7f;
    float w1 = g2 - g0, h1 = (g3 - g1) + E;
    float w2 = p2 - p0, h2 = (p3 - p1) + E;
    float iw = fminf(g2, p2) - fmaxf(g0, p0); iw = fmaxf(iw, 0.f);
    float ih = fminf(g3, p3) - fmaxf(g1, p1); ih = fmaxf(ih, 0.f);
    float inter = iw * ih;
    float uni = w1 * h1 + w2 * h2 - inter + E;
    float iou = inter / uni;
    float cw = fmaxf(g2, p2) - fminf(g0, p0);
    float ch = fmaxf(g3, p3) - fminf(g1, p1);
    float c2 = cw * cw + ch * ch + E;
    float dx = p0 + p2 - g0 - g2;
    float dy = p1 + p3 - g1 - g3;
    float rho2 = (dx * dx + dy * dy) / 4.0f;
    float da = atanf(w2 / h2) - atanf(w1 / h1);
    float v = 0.4052847345693511f * (da * da);
    float alpha = v / ((v - iou) + 1.0000001f);
    return iou - (rho2 / c2 + v * alpha);
}

// One cooperative persistent kernel: all 6 phases, grid.sync() between them.
// 512 blocks x 256 thr = 2 blocks/CU co-resident (LDS 32.25KB/block, VGPR<=256).
__global__ __launch_bounds__(256, 2) void tal_fused(
    const float* __restrict__ pd_scores,
    const float* __restrict__ pd_bboxes,
    const float* __restrict__ anc,
    const int* __restrict__ gt_labels,
    const float* __restrict__ gt_bboxes,
    const float* __restrict__ mask_gt,
    float* __restrict__ out,
    int* zero_base,          // contiguous: cnt | jA | qcnt | posA | posO | mcount
    int* cnt, int* jA, int* qcnt, unsigned* posA, unsigned* posO, int* mcount,
    float* av, int* tk_a, int* tk_f, float* tk_v, float* tk_o,
    int* mlist, int* qlist)
{
    cg::grid_group gg = cg::this_grid();
    const int tid = blockIdx.x * NTHR + threadIdx.x;
    const int lane = threadIdx.x & 63;

    // per-wave private candidate buffers for P2 (no barriers needed)
    __shared__ int   s_ca[4][CMAX];
    __shared__ float s_cv[4][CMAX];
    __shared__ float s_co[4][CMAX];

    // ================= P0: zero-init workspace =================
    for (int i = tid; i < ZWORDS; i += TTOT) zero_base[i] = 0;
    gg.sync();

    // ================= P1: inverted in-box scan =================
    // wave lanes = consecutive anchors of one batch; box/mask loads uniform.
    for (int idx = tid; idx < BS * NAP; idx += TTOT) {
        int b = idx / NAP; int a = idx - b * NAP;
        bool inr = a < NA;
        float2 ap = inr ? *(const float2*)&anc[2 * a] : make_float2(-1e9f, -1e9f);
        for (int j = 0; j < NB; j++) {
            int r = b * NB + j;
            float mg = mask_gt[r];                        // uniform -> s_load
            float4 g = *(const float4*)&gt_bboxes[r * 4]; // uniform -> s_load
            float d0 = ap.x - g.x, d1 = ap.y - g.y, d2 = g.z - ap.x, d3 = g.w - ap.y;
            float dmin = fminf(fminf(d0, d1), fminf(d2, d3));
            bool hit = inr && (mg > 0.f) && (dmin > 1e-9f);
            unsigned long long m = __ballot(hit);
            if (m) {
                int rank = __popcll(m & ((1ull << lane) - 1ull));
                int ldr = __ffsll((long long)m) - 1;
                int base = 0;
                if (lane == ldr) base = atomicAdd(&qcnt[r], __popcll(m));
                base = __shfl(base, ldr);
                int p = base + rank;
                if (hit && p < QCAP) qlist[r * QCAP + p] = a;
            }
        }
    }
    gg.sync();

    // ================= P2: per-row dense metrics + wave top-13 =================
    // One wave per gt row (2048 waves = 2048 rows). Candidate set = in-box anchors
    // U {anchors 0..31 not in-box} (sufficient for top_k zero-padding tie-break:
    // zeros picked only when npos<13 -> >=20 zero candidates with idx<32 exist).
    {
        int wv = threadIdx.x >> 6;
        int r = blockIdx.x * 4 + wv;     // 512*4 = 2048 = BS*NB
        int b = r >> 6;
        int* ca = s_ca[wv]; float* cv = s_cv[wv]; float* co = s_co[wv];

        if (mask_gt[r] <= 0.f) {
            if (lane < TK) {
                tk_a[r * TK + lane] = 0; tk_v[r * TK + lane] = 0.f;
                tk_o[r * TK + lane] = 0.f; tk_f[r * TK + lane] = 0;
            }
        } else {
            float4 g = *(const float4*)&gt_bboxes[r * 4];
            int lbl = gt_labels[r];
            int n0 = min(qcnt[r], QCAP);

            bool add = false;
            if (lane < FORCED) {
                float2 ap = *(const float2*)&anc[2 * lane];
                float d0 = ap.x - g.x, d1 = ap.y - g.y, d2 = g.z - ap.x, d3 = g.w - ap.y;
                float dmin = fminf(fminf(d0, d1), fminf(d2, d3));
                add = !(dmin > 1e-9f);
            }
            unsigned long long mb = __ballot(add);
            int pos = __popcll(mb & ((1ull << lane) - 1ull));
            if (add) { ca[n0 + pos] = lane; cv[n0 + pos] = 0.f; co[n0 + pos] = 0.f; }
            int n = n0 + __popcll(mb);

            for (int c = lane; c < n0; c += 64) {
                int a = qlist[r * QCAP + c];
                float4 p = *(const float4*)&pd_bboxes[(b * NA + a) * 4];
                float ov = fmaxf(ciou_f(g.x, g.y, g.z, g.w, p.x, p.y, p.z, p.w), 0.f);
                float sc = pd_scores[(b * NA + a) * NC + lbl];
                float o2 = ov * ov;
                ca[c] = a | (1 << 30); cv[c] = sc * (o2 * o2 * o2); co[c] = ov;
            }
            // wave-private LDS; within-wave DS ordering handled by compiler waitcnts

            unsigned consumed = 0;
            int wslot = 0; float wval = 0.f;
            for (int round = 0; round < TK; round++) {
                float bv = -2.f; int bgi = 0x7fffffff; int bsl = 0;
                int li = 0;
                for (int c = lane; c < n; c += 64, li++) {
                    if (consumed & (1u << li)) continue;
                    float v = cv[c]; int gi = ca[c] & 0x3fffffff;
                    if (v > bv || (v == bv && gi < bgi)) { bv = v; bgi = gi; bsl = c; }
                }
                for (int off = 32; off; off >>= 1) {
                    float v2 = __shfl_down(bv, off);
                    int  gi2 = __shfl_down(bgi, off);
                    int  sl2 = __shfl_down(bsl, off);
                    if (v2 > bv || (v2 == bv && gi2 < bgi)) { bv = v2; bgi = gi2; bsl = sl2; }
                }
                int wsl = __shfl(bsl, 0);
                float wvv = __shfl(bv, 0);
                if ((wsl & 63) == lane) consumed |= 1u << (wsl >> 6);
                if (lane == round) { wslot = wsl; wval = wvv; }
            }
            if (lane < TK) {
                int packed = ca[wslot]; int a = packed & 0x3fffffff; int in = (packed >> 30) & 1;
                tk_a[r * TK + lane] = a;
                tk_v[r * TK + lane] = wval;
                tk_o[r * TK + lane] = co[wslot];
                tk_f[r * TK + lane] = in;
                if (in) atomicAdd(&cnt[b * NA + a], 1);
            }
        }
    }
    gg.sync();

    // ================= P3: singles assigned + pos maxes; multis claimed ============
    // jA encoding: 0 = unassigned, -1 = claimed multi, j+1 = assigned to row j.
    for (int c = tid; c < NCAND; c += TTOT) {
        if (!tk_f[c]) continue;
        int r = c / TK; int b = r >> 6; int j = r & 63;
        int a = tk_a[c];
        int i = b * NA + a;
        if (cnt[i] == 1) {
            jA[i] = j + 1; av[i] = tk_v[c];
            atomicMax(&posA[b * NB + j], __float_as_uint(tk_v[c]));  // values >= 0
            atomicMax(&posO[b * NB + j], __float_as_uint(tk_o[c]));
        } else {
            int old = atomicCAS(&jA[i], 0, -1);
            if (old == 0) { int p = atomicAdd(mcount, 1); mlist[p] = i; }
        }
    }
    gg.sync();

    // ================= P4: multi anchors — one wave per anchor, lanes = gt rows ====
    {
        int wid = tid >> 6;
        int nm = *mcount;
        for (int e = wid; e < nm; e += TTOT / 64) {
            int i = mlist[e];
            int b = i / NA, a = i - b * NA;
            float2 ap = *(const float2*)&anc[2 * a];
            int row = b * NB + lane;
            float o = 0.f;
            if (mask_gt[row] > 0.f) {
                float4 g = *(const float4*)&gt_bboxes[row * 4];
                float d0 = ap.x - g.x, d1 = ap.y - g.y, d2 = g.z - ap.x, d3 = g.w - ap.y;
                float dmin = fminf(fminf(d0, d1), fminf(d2, d3));
                if (dmin > 1e-9f) {
                    float4 p = *(const float4*)&pd_bboxes[(b * NA + a) * 4];
                    o = fmaxf(ciou_f(g.x, g.y, g.z, g.w, p.x, p.y, p.z, p.w), 0.f);
                }
            }
            float bv = o; int bj = lane;                  // argmax, lowest j on ties
            for (int off = 32; off; off >>= 1) {
                float v2 = __shfl_down(bv, off);
                int  j2 = __shfl_down(bj, off);
                if (v2 > bv || (v2 == bv && j2 < bj)) { bv = v2; bj = j2; }
            }
            if (lane == 0) {
                int lbl = gt_labels[b * NB + bj];
                float sc = pd_scores[(b * NA + a) * NC + lbl];
                float o2 = bv * bv;
                float alg = sc * (o2 * o2 * o2);          // masked ov=0 -> alg=0
                jA[i] = bj + 1; av[i] = alg;
                atomicMax(&posA[b * NB + bj], __float_as_uint(alg));
                atomicMax(&posO[b * NB + bj], __float_as_uint(bv));
            }
        }
    }
    gg.sync();

    // ================= P5: all outputs =================
    float* o_sc = out + BS * NA * 5;
    for (int t = tid; t < BS * NA * 20; t += TTOT) {       // scores: float4 per thread
        int row = t / 20;
        int q = t - row * 20;
        int b = row / NA;
        int jj1 = jA[row];
        int tg = jj1 > 0 ? jj1 - 1 : 0;
        int lab = gt_labels[b * NB + tg]; lab = lab < 0 ? 0 : lab;
        float nrm = 0.f;
        if (jj1 > 0) {
            float pa = __uint_as_float(posA[b * NB + tg]);
            float po = __uint_as_float(posO[b * NB + tg]);
            nrm = (av[row] * po) / (pa + 1e-9f);
        }
        int c4 = q * 4;
        int cls = (jj1 > 0) ? lab : -1;
        floatx4 v;
        v.x = (c4 + 0 == cls) ? nrm : 0.f;
        v.y = (c4 + 1 == cls) ? nrm : 0.f;
        v.z = (c4 + 2 == cls) ? nrm : 0.f;
        v.w = (c4 + 3 == cls) ? nrm : 0.f;
        *(floatx4*)&o_sc[row * NC + c4] = v;
    }
    float* o_lab  = out;                          // (bs,na)
    float* o_bbox = out + BS * NA;                // (bs,na,4)
    float* o_fg   = out + BS * NA * (5 + NC);     // (bs,na) bool as float
    float* o_idx  = o_fg + BS * NA;               // (bs,na)
    for (int row = tid; row < BS * NA; row += TTOT) {      // small per-anchor outputs
        int b = row / NA;
        int jj1 = jA[row];
        int tg = jj1 > 0 ? jj1 - 1 : 0;
        int lab = gt_labels[b * NB + tg]; lab = lab < 0 ? 0 : lab;
        o_lab[row] = (float)lab;
        float4 bb = *(const float4*)&gt_bboxes[(b * NB + tg) * 4];  // exact passthrough
        *(float4*)&o_bbox[row * 4] = bb;
        o_fg[row] = (jj1 > 0) ? 1.f : 0.f;
        o_idx[row] = (float)tg;
    }
}

extern "C" void kernel_launch(void* const* d_in, const int* in_sizes, int n_in,
                              void* d_out, int out_size, void* d_ws, size_t ws_size,
                              hipStream_t stream) {
    const float* pd_scores = (const float*)d_in[0];
    const float* pd_bboxes = (const float*)d_in[1];
    const float* anc       = (const float*)d_in[2];
    const int*   gt_labels = (const int*)d_in[3];
    const float* gt_bboxes = (const float*)d_in[4];
    const float* mask_gt   = (const float*)d_in[5];
    float* out = (float*)d_out;

    char* w = (char*)d_ws;
    // ---- zero-init region (P0) ----
    int*      zero_base = (int*)w;
    int*      cnt  = (int*)w;      w += BS * NA * 4;
    int*      jA   = (int*)w;      w += BS * NA * 4;          // 0 = unassigned
    int*      qcnt = (int*)w;      w += BS * NB * 4;
    unsigned* posA = (unsigned*)w; w += BS * NB * 4;
    unsigned* posO = (unsigned*)w; w += BS * NB * 4;
    int*      mcount = (int*)w;    w += 64;
    // ---- no-init scratch ----
    float*    av   = (float*)w;    w += BS * NA * 4;
    int*      tk_a = (int*)w;      w += NCAND * 4;
    int*      tk_f = (int*)w;      w += NCAND * 4;
    float*    tk_v = (float*)w;    w += NCAND * 4;
    float*    tk_o = (float*)w;    w += NCAND * 4;
    int*      mlist = (int*)w;     w += NCAND * 4;
    int*      qlist = (int*)w;     w += BS * NB * QCAP * 4;   // 5.24 MB

    void* args[] = {
        (void*)&pd_scores, (void*)&pd_bboxes, (void*)&anc,
        (void*)&gt_labels, (void*)&gt_bboxes, (void*)&mask_gt,
        (void*)&out,
        (void*)&zero_base,
        (void*)&cnt, (void*)&jA, (void*)&qcnt, (void*)&posA, (void*)&posO,
        (void*)&mcount,
        (void*)&av, (void*)&tk_a, (void*)&tk_f, (void*)&tk_v, (void*)&tk_o,
        (void*)&mlist, (void*)&qlist
    };
    hipLaunchCooperativeKernel((const void*)tal_fused, dim3(NBLK), dim3(NTHR),
                               args, 0, stream);
}

// Round 8
// 262.788 us; speedup vs baseline: 2.0703x; 2.0703x over previous
//
#include <hip/hip_runtime.h>
#include <stdint.h>

#pragma clang fp contract(off)

#define BS 32
#define NB 64
#define NA 8400
#define NC 80
#define TK 13
#define QCAP 640          // max in-box anchors per gt row (expected <=~400)
#define CMAX (QCAP + 32)  // + forced anchors
#define FORCED 32

typedef float floatx4 __attribute__((ext_vector_type(4)));

// ---------- CIoU, numpy op order, no FMA contraction ----------
__device__ __forceinline__ float ciou_f(float g0, float g1, float g2, float g3,
                                        float p0, float p1, float p2, float p3) {
    const float E = 1e-7f;
    float w1 = g2 - g0, h1 = (g3 - g1) + E;
    float w2 = p2 - p0, h2 = (p3 - p1) + E;
    float iw = fminf(g2, p2) - fmaxf(g0, p0); iw = fmaxf(iw, 0.f);
    float ih = fminf(g3, p3) - fmaxf(g1, p1); ih = fmaxf(ih, 0.f);
    float inter = iw * ih;
    float uni = w1 * h1 + w2 * h2 - inter + E;
    float iou = inter / uni;
    float cw = fmaxf(g2, p2) - fminf(g0, p0);
    float ch = fmaxf(g3, p3) - fminf(g1, p1);
    float c2 = cw * cw + ch * ch + E;
    float dx = p0 + p2 - g0 - g2;
    float dy = p1 + p3 - g1 - g3;
    float rho2 = (dx * dx + dy * dy) / 4.0f;
    float da = atanf(w2 / h2) - atanf(w1 / h1);
    float v = 0.4052847345693511f * (da * da);
    float alpha = v / ((v - iou) + 1.0000001f);
    return iou - (rho2 / c2 + v * alpha);
}

// ========== K1a: inverted scan — thread owns an anchor, loops 64 uniform boxes =====
// b = blockIdx.y is block-uniform -> mask/box loads scalarize to s_load;
// wave-aggregated queue append (one atomic per wave-hit-group).
__global__ __launch_bounds__(256) void k1a_scan(
    const float* __restrict__ anc,
    const float* __restrict__ gt_bboxes,
    const float* __restrict__ mask_gt,
    int* __restrict__ qcnt, int* __restrict__ qlist)
{
    int b = blockIdx.y;
    int a = blockIdx.x * 256 + threadIdx.x;
    int lane = threadIdx.x & 63;
    bool inrange = a < NA;
    float2 ap = inrange ? *(const float2*)&anc[2 * a] : make_float2(-1e9f, -1e9f);
    for (int j = 0; j < NB; j++) {
        int r = b * NB + j;
        float mg = mask_gt[r];                        // uniform -> s_load
        float4 g = *(const float4*)&gt_bboxes[r * 4]; // uniform -> s_load_dwordx4
        float d0 = ap.x - g.x, d1 = ap.y - g.y, d2 = g.z - ap.x, d3 = g.w - ap.y;
        float dmin = fminf(fminf(d0, d1), fminf(d2, d3));
        bool hit = inrange && (mg > 0.f) && (dmin > 1e-9f);
        unsigned long long m = __ballot(hit);
        if (m) {
            int rank = __popcll(m & ((1ull << lane) - 1ull));
            int ldr = __ffsll((long long)m) - 1;
            int base = 0;
            if (lane == ldr) base = atomicAdd(&qcnt[r], __popcll(m));
            base = __shfl(base, ldr);
            int p = base + rank;
            if (hit && p < QCAP) qlist[r * QCAP + p] = a;
        }
    }
}

// ========== K1b: per-row dense metrics over queue + forced anchors, wave top-13 ====
// Candidate set = {in-box anchors} U {anchors 0..31 not in-box}. Sufficiency of the
// forced set for top_k's zero-padding tie-break: zeros are picked only when npos<13;
// then >=20 zero candidates with idx<32 exist, and the reference's picked zeros
// (lowest-index zeros globally) all have idx<32. Dedup: in-box a<32 only in queue.
// Also bumps per-anchor fg count (fused k2b) for in-box winners.
__global__ __launch_bounds__(64) void k1b_topk(
    const float* __restrict__ pd_scores,
    const float* __restrict__ pd_bboxes,
    const float* __restrict__ anc,
    const int* __restrict__ gt_labels,
    const float* __restrict__ gt_bboxes,
    const float* __restrict__ mask_gt,
    const int* __restrict__ qcnt, const int* __restrict__ qlist,
    int* __restrict__ tk_a, float* __restrict__ tk_v,
    float* __restrict__ tk_o, int* __restrict__ tk_f,
    int* __restrict__ cnt)
{
    int r = blockIdx.x;              // b*NB + j
    int b = r >> 6;
    int lane = threadIdx.x;          // one wave per row

    if (mask_gt[r] <= 0.f) {         // masked row contributes nothing downstream
        if (lane < TK) {
            tk_a[r * TK + lane] = 0; tk_v[r * TK + lane] = 0.f;
            tk_o[r * TK + lane] = 0.f; tk_f[r * TK + lane] = 0;
        }
        return;
    }

    __shared__ int   ca[CMAX];       // bit30 = in-box flag, low bits = anchor idx
    __shared__ float cv[CMAX];
    __shared__ float co[CMAX];

    float4 g = *(const float4*)&gt_bboxes[r * 4];
    int lbl = gt_labels[r];
    int n0 = min(qcnt[r], QCAP);

    // forced anchors 0..31 that are NOT in-box -> zero candidates (ballot compact)
    bool add = false;
    if (lane < FORCED) {
        float2 ap = *(const float2*)&anc[2 * lane];
        float d0 = ap.x - g.x, d1 = ap.y - g.y, d2 = g.z - ap.x, d3 = g.w - ap.y;
        float dmin = fminf(fminf(d0, d1), fminf(d2, d3));
        add = !(dmin > 1e-9f);
    }
    unsigned long long mb = __ballot(add);
    int pos = __popcll(mb & ((1ull << lane) - 1ull));
    if (add) { ca[n0 + pos] = lane; cv[n0 + pos] = 0.f; co[n0 + pos] = 0.f; }
    int n = n0 + __popcll(mb);

    // dense CIoU + align over queue entries (all lanes active)
    for (int c = lane; c < n0; c += 64) {
        int a = qlist[r * QCAP + c];
        float4 p = *(const float4*)&pd_bboxes[(b * NA + a) * 4];
        float ov = fmaxf(ciou_f(g.x, g.y, g.z, g.w, p.x, p.y, p.z, p.w), 0.f);
        float sc = pd_scores[(b * NA + a) * NC + lbl];
        float o2 = ov * ov;
        ca[c] = a | (1 << 30); cv[c] = sc * (o2 * o2 * o2); co[c] = ov;
    }
    __syncthreads();

    // top-13: 13 rounds of wave argmax with per-lane consumed bitmask (<=11 slots)
    // tie-break identical to top_k / stable argsort: value desc, global index asc.
    unsigned consumed = 0;
    int wslot = 0; float wval = 0.f;
    for (int round = 0; round < TK; round++) {
        float bv = -2.f; int bgi = 0x7fffffff; int bsl = 0;
        int li = 0;
        for (int c = lane; c < n; c += 64, li++) {
            if (consumed & (1u << li)) continue;
            float v = cv[c]; int gi = ca[c] & 0x3fffffff;
            if (v > bv || (v == bv && gi < bgi)) { bv = v; bgi = gi; bsl = c; }
        }
        for (int off = 32; off; off >>= 1) {
            float v2 = __shfl_down(bv, off);
            int  gi2 = __shfl_down(bgi, off);
            int  sl2 = __shfl_down(bsl, off);
            if (v2 > bv || (v2 == bv && gi2 < bgi)) { bv = v2; bgi = gi2; bsl = sl2; }
        }
        int wsl = __shfl(bsl, 0);
        float wv = __shfl(bv, 0);
        if ((wsl & 63) == lane) consumed |= 1u << (wsl >> 6);
        if (lane == round) { wslot = wsl; wval = wv; }
    }
    if (lane < TK) {
        int packed = ca[wslot]; int a = packed & 0x3fffffff; int in = (packed >> 30) & 1;
        tk_a[r * TK + lane] = a;
        tk_v[r * TK + lane] = wval;
        tk_o[r * TK + lane] = co[wslot];
        tk_f[r * TK + lane] = in;    // mask_pos_pre = in_topk && in_gts && mgt
        if (in) atomicAdd(&cnt[b * NA + a], 1);       // fused k2b
    }
}

// ========== K2c: singles assigned + pos maxes; multi anchors claimed into list =====
// jA encoding: 0 = unassigned, -1 = claimed multi, j+1 = assigned to row j.
__global__ void k2c_single(const int* __restrict__ tk_a, const float* __restrict__ tk_v,
                           const float* __restrict__ tk_o, const int* __restrict__ tk_f,
                           const int* __restrict__ cnt, int* __restrict__ jA,
                           float* __restrict__ av,
                           unsigned* __restrict__ posA, unsigned* __restrict__ posO,
                           int* __restrict__ mlist, int* __restrict__ mcount) {
    int c = blockIdx.x * 256 + threadIdx.x;
    if (c >= BS * NB * TK) return;
    if (!tk_f[c]) return;
    int r = c / TK; int b = r >> 6; int j = r & 63;
    int a = tk_a[c];
    int i = b * NA + a;
    if (cnt[i] == 1) {
        jA[i] = j + 1; av[i] = tk_v[c];
        atomicMax(&posA[b * NB + j], __float_as_uint(tk_v[c]));   // values >= 0
        atomicMax(&posO[b * NB + j], __float_as_uint(tk_o[c]));
    } else {
        int old = atomicCAS(&jA[i], 0, -1);
        if (old == 0) { int p = atomicAdd(mcount, 1); mlist[p] = i; }
    }
}

// ========== K2d: multi anchors, one wave per anchor, lanes = 64 gt rows ============
__global__ __launch_bounds__(256) void k2d_multi(
    const float* __restrict__ pd_scores,
    const float* __restrict__ pd_bboxes,
    const float* __restrict__ anc,
    const int* __restrict__ gt_labels,
    const float* __restrict__ gt_bboxes,
    const float* __restrict__ mask_gt,
    const int* __restrict__ mlist, const int* __restrict__ mcount,
    int* __restrict__ jA, float* __restrict__ av,
    unsigned* __restrict__ posA, unsigned* __restrict__ posO)
{
    int wid = (blockIdx.x * 256 + threadIdx.x) >> 6;
    int lane = threadIdx.x & 63;
    int nwaves = (gridDim.x * 256) >> 6;
    int nm = *mcount;
    for (int e = wid; e < nm; e += nwaves) {
        int i = mlist[e];
        int b = i / NA, a = i - b * NA;
        float2 ap = *(const float2*)&anc[2 * a];
        int row = b * NB + lane;
        float o = 0.f;
        if (mask_gt[row] > 0.f) {
            float4 g = *(const float4*)&gt_bboxes[row * 4];
            float d0 = ap.x - g.x, d1 = ap.y - g.y, d2 = g.z - ap.x, d3 = g.w - ap.y;
            float dmin = fminf(fminf(d0, d1), fminf(d2, d3));
            if (dmin > 1e-9f) {
                float4 p = *(const float4*)&pd_bboxes[(b * NA + a) * 4];
                o = fmaxf(ciou_f(g.x, g.y, g.z, g.w, p.x, p.y, p.z, p.w), 0.f);
            }
        }
        float bv = o; int bj = lane;                   // argmax, lowest j wins ties
        for (int off = 32; off; off >>= 1) {
            float v2 = __shfl_down(bv, off);
            int  j2 = __shfl_down(bj, off);
            if (v2 > bv || (v2 == bv && j2 < bj)) { bv = v2; bj = j2; }
        }
        if (lane == 0) {
            int lbl = gt_labels[b * NB + bj];
            float sc = pd_scores[(b * NA + a) * NC + lbl];
            float o2 = bv * bv;
            float alg = sc * (o2 * o2 * o2);           // masked ov=0 -> alg=0
            jA[i] = bj + 1; av[i] = alg;
            atomicMax(&posA[b * NB + bj], __float_as_uint(alg));
            atomicMax(&posO[b * NB + bj], __float_as_uint(bv));
        }
    }
}

// ========== K3: all outputs — scores (one-hot*norm) + per-anchor smalls, fused =====
// 20 threads per anchor-row; each stores one float4 of the 80-class row.
// REGULAR stores (L2-cached): nontemporal stores measured ~+60us across R5/R6.
__global__ __launch_bounds__(256) void k3_final(
    const int* __restrict__ gt_labels,
    const float* __restrict__ gt_bboxes,
    const int* __restrict__ jA, const float* __restrict__ av,
    const unsigned* __restrict__ posA, const unsigned* __restrict__ posO,
    float* __restrict__ out)
{
    int t = blockIdx.x * 256 + threadIdx.x;          // BS*NA*20 = 5,376,000 exactly
    int row = t / 20;                                // i = b*NA + a
    int q = t - row * 20;
    int b = row / NA;
    int jj1 = jA[row];                               // 0 = background, j+1 otherwise
    int tg = jj1 > 0 ? jj1 - 1 : 0;
    int lab = gt_labels[b * NB + tg]; lab = lab < 0 ? 0 : lab;

    float nrm = 0.f;
    if (jj1 > 0) {
        float pa = __uint_as_float(posA[b * NB + tg]);
        float po = __uint_as_float(posO[b * NB + tg]);
        nrm = (av[row] * po) / (pa + 1e-9f);
    }

    int c4 = q * 4;
    int cls = (jj1 > 0) ? lab : -1;
    floatx4 v;
    v.x = (c4 + 0 == cls) ? nrm : 0.f;
    v.y = (c4 + 1 == cls) ? nrm : 0.f;
    v.z = (c4 + 2 == cls) ? nrm : 0.f;
    v.w = (c4 + 3 == cls) ? nrm : 0.f;
    float* o_sc = out + BS * NA * 5;
    *(floatx4*)&o_sc[row * NC + c4] = v;

    if (q == 0) {
        float* o_lab  = out;                          // (bs,na)
        float* o_bbox = out + BS * NA;                // (bs,na,4)
        float* o_fg   = out + BS * NA * (5 + NC);     // (bs,na) bool as float
        float* o_idx  = o_fg + BS * NA;               // (bs,na)
        o_lab[row] = (float)lab;
        float4 bb = *(const float4*)&gt_bboxes[(b * NB + tg) * 4];  // exact passthrough
        *(float4*)&o_bbox[row * 4] = bb;
        o_fg[row] = (jj1 > 0) ? 1.f : 0.f;
        o_idx[row] = (float)tg;
    }
}

extern "C" void kernel_launch(void* const* d_in, const int* in_sizes, int n_in,
                              void* d_out, int out_size, void* d_ws, size_t ws_size,
                              hipStream_t stream) {
    const float* pd_scores = (const float*)d_in[0];
    const float* pd_bboxes = (const float*)d_in[1];
    const float* anc       = (const float*)d_in[2];
    const int*   gt_labels = (const int*)d_in[3];
    const float* gt_bboxes = (const float*)d_in[4];
    const float* mask_gt   = (const float*)d_in[5];
    float* out = (float*)d_out;

    char* w = (char*)d_ws;
    const int NCAND = BS * NB * TK;      // 26624
    // ---- zero-init region (single memset) ----
    char* zbase = w;
    int*      cnt  = (int*)w;      w += BS * NA * 4;
    int*      jA   = (int*)w;      w += BS * NA * 4;          // 0 = unassigned
    int*      qcnt = (int*)w;      w += BS * NB * 4;
    unsigned* posA = (unsigned*)w; w += BS * NB * 4;
    unsigned* posO = (unsigned*)w; w += BS * NB * 4;
    int*      mcount = (int*)w;    w += 64;
    size_t zbytes = (size_t)(w - zbase);
    // ---- no-init scratch ----
    float*    av   = (float*)w;    w += BS * NA * 4;
    int*      tk_a = (int*)w;      w += NCAND * 4;
    int*      tk_f = (int*)w;      w += NCAND * 4;
    float*    tk_v = (float*)w;    w += NCAND * 4;
    float*    tk_o = (float*)w;    w += NCAND * 4;
    int*      mlist = (int*)w;     w += NCAND * 4;
    int*      qlist = (int*)w;     w += BS * NB * QCAP * 4;   // 5.24 MB

    hipMemsetAsync(zbase, 0, zbytes, stream);
    {
        dim3 g((NA + 255) / 256, BS);
        k1a_scan<<<g, 256, 0, stream>>>(anc, gt_bboxes, mask_gt, qcnt, qlist);
    }
    k1b_topk<<<BS * NB, 64, 0, stream>>>(pd_scores, pd_bboxes, anc, gt_labels,
                                         gt_bboxes, mask_gt, qcnt, qlist,
                                         tk_a, tk_v, tk_o, tk_f, cnt);
    k2c_single<<<(NCAND + 255) / 256, 256, 0, stream>>>(tk_a, tk_v, tk_o, tk_f,
                                                        cnt, jA, av, posA, posO,
                                                        mlist, mcount);
    k2d_multi<<<52, 256, 0, stream>>>(pd_scores, pd_bboxes, anc, gt_labels,
                                      gt_bboxes, mask_gt, mlist, mcount,
                                      jA, av, posA, posO);
    k3_final<<<BS * NA * 20 / 256, 256, 0, stream>>>(gt_labels, gt_bboxes, jA, av,
                                                     posA, posO, out);
}